// Round 11
// baseline (693.154 us; speedup 1.0000x reference)
//
#include <hip/hip_runtime.h>
#include <math.h>

#define B_ 64
#define S_ 64
#define U_ 16
#define EMB_ 10
#define D_ 34
#define DD_ 3
#define FF_ 4
#define NL_ 4

typedef float v2f __attribute__((ext_vector_type(2)));

#define PIN(x) asm volatile("" : "+v"(x))

template <int N> struct IC { static constexpr int value = N; };

template <int CTRL>
__device__ __forceinline__ void dpp4(float& a, float& b, float& c, float& d) {
    int ta = __builtin_amdgcn_update_dpp(0, __float_as_int(a), CTRL, 0xf, 0xf, true);
    int tb = __builtin_amdgcn_update_dpp(0, __float_as_int(b), CTRL, 0xf, 0xf, true);
    int tc = __builtin_amdgcn_update_dpp(0, __float_as_int(c), CTRL, 0xf, 0xf, true);
    int td = __builtin_amdgcn_update_dpp(0, __float_as_int(d), CTRL, 0xf, 0xf, true);
    a += __int_as_float(ta);
    b += __int_as_float(tb);
    c += __int_as_float(tc);
    d += __int_as_float(td);
}

__device__ __forceinline__ void red16_4(float& a, float& b, float& c, float& d) {
    dpp4<0x111>(a, b, c, d);
    dpp4<0x112>(a, b, c, d);
    dpp4<0x114>(a, b, c, d);
    dpp4<0x118>(a, b, c, d);   // lane 15 of each row = row sum
}

template <int L>
__device__ __forceinline__ float rlane(float v) {
    return __int_as_float(__builtin_amdgcn_readlane(__float_as_int(v), L));
}

__device__ __forceinline__ void ln3e(float z0, float z1, float z2,
                                     float w0, float w1, float w2,
                                     float b0, float b1, float b2,
                                     float& o0, float& o1, float& o2) {
    float s1 = (z0 + z1) + z2;
    float s2 = fmaf(z0, z0, fmaf(z1, z1, z2 * z2));
    float mu = s1 * (1.0f / 3.0f);
    float vpe = fmaf(s2, (1.0f / 3.0f), fmaf(-mu, mu, 1e-5f));
    float rstd = __builtin_amdgcn_rsqf(vpe);
    o0 = fmaf(z0 - mu, rstd * w0, b0);
    o1 = fmaf(z1 - mu, rstd * w1, b1);
    o2 = fmaf(z2 - mu, rstd * w2, b2);
}

// Self-resetting handshake flags (zero-initialized at module load; the last
// decoder block of each iteration resets both -> graph replay safe).
__device__ int g_flagA;   // enc blocks completed (0 -> 64)
__device__ int g_flagB;   // dec blocks completed (0 -> 64)

// ---------------------------------------------------------------------------
// R25: FUSED kernel. Blocks 0..63 = encoder (EXACT R13 body) + release
// signal; blocks 64..127 = decoder (EXACT R24 body) with the mem-independent
// weight prologue hoisted BEFORE an acquire-spin on the flag (overlaps enc),
// and the mem-dependent cross-attn folds after it. Eliminates the
// inter-kernel launch gap and hides the dec prologue under enc.
// Capacity: 128 blocks <= 256 CUs -> all co-resident, no deadlock.
// ---------------------------------------------------------------------------
__global__ __launch_bounds__(512) void fused_kernel(
    const float* __restrict__ src, const float* __restrict__ wemb,
    const float* __restrict__ semb,
    const float* __restrict__ qkv_w, const float* __restrict__ qkv_b,
    const float* __restrict__ out_w, const float* __restrict__ out_b,
    const float* __restrict__ ln1_w, const float* __restrict__ ln1_b,
    const float* __restrict__ lin1_w, const float* __restrict__ lin1_b,
    const float* __restrict__ lin2_w, const float* __restrict__ lin2_b,
    const float* __restrict__ ln2_w, const float* __restrict__ ln2_b,
    const float* __restrict__ norm_w, const float* __restrict__ norm_b,
    const float* __restrict__ eo_w, const float* __restrict__ eo_b,
    const float* __restrict__ sa_qkv_w, const float* __restrict__ sa_qkv_b,
    const float* __restrict__ sa_out_w, const float* __restrict__ sa_out_b,
    const float* __restrict__ gln1_w, const float* __restrict__ gln1_b,
    const float* __restrict__ ca_qkv_w, const float* __restrict__ ca_qkv_b,
    const float* __restrict__ ca_out_w, const float* __restrict__ ca_out_b,
    const float* __restrict__ gln2_w, const float* __restrict__ gln2_b,
    const float* __restrict__ l1_w, const float* __restrict__ l1_b,
    const float* __restrict__ l2_w, const float* __restrict__ l2_b,
    const float* __restrict__ gln3_w, const float* __restrict__ gln3_b,
    float* __restrict__ mem, float* __restrict__ out)
{
    const int tid = threadIdx.x;

    if (blockIdx.x < 64) {
        // ===================== ENCODER (exact R13 body) =====================
        const int b = blockIdx.x;
        const int wv_ = tid >> 6;
        const int lane = tid & 63;

        __shared__ float xs[S_][D_ + 1];
        __shared__ float tmp[S_][D_ + 1];
        __shared__ float att[S_][D_ + 1];
        __shared__ __align__(16) float qsh[2][S_][21];
        __shared__ __align__(16) float ksh[2][S_][20];
        __shared__ __align__(16) float vsh[2][S_][20];
        __shared__ float ffh[S_][5];
        __shared__ float pacc[4][128][19];

        const float rs17 = 0.24253562503633297f;
        const float negln = -logf(10000.0f) / (float)D_;

        #pragma unroll
        for (int rr = 0; rr < 5; ++rr) {
            int idx = tid + rr * 512;
            if (idx < S_ * D_) {
                int pos = idx / D_, d = idx % D_;
                float v;
                if (d < U_ - 2) {
                    v = src[(b * S_ + pos) * U_ + d];
                } else if (d < U_ - 2 + EMB_) {
                    int wi = (int)src[(b * S_ + pos) * U_ + (U_ - 2)];
                    v = wemb[wi * EMB_ + (d - (U_ - 2))];
                } else {
                    int si = (int)src[(b * S_ + pos) * U_ + (U_ - 1)];
                    v = semb[si * EMB_ + (d - (U_ - 2 + EMB_))];
                }
                int k = d >> 1;
                float div = __expf((float)(2 * k) * negln);
                float ang = (float)b * div;
                v += (d & 1) ? __cosf(ang) : __sinf(ang);
                xs[pos][d] = v;
            }
        }
        __syncthreads();

        for (int l = 0; l < NL_; ++l) {
            const float* Wq = qkv_w + l * 3 * D_ * D_;
            const float* Bq = qkv_b + l * 3 * D_;

            {
                v2f xr2[17];
                #pragma unroll
                for (int d2 = 0; d2 < 17; ++d2) {
                    v2f t; t.x = xs[lane][2 * d2]; t.y = xs[lane][2 * d2 + 1];
                    xr2[d2] = t;
                }
                #pragma unroll
                for (int rb = 0; rb < 13; ++rb) {
                    int r = wv_ + (rb << 3);
                    if (r < 3 * D_) {
                        int ru = __builtin_amdgcn_readfirstlane(r);
                        const v2f* w2 = (const v2f*)(Wq + ru * D_);
                        v2f a2; a2.x = Bq[ru]; a2.y = 0.f;
                        #pragma unroll
                        for (int d2 = 0; d2 < 17; ++d2)
                            a2 = __builtin_elementwise_fma(xr2[d2], w2[d2], a2);
                        float acc = a2.x + a2.y;
                        if (ru < D_)          { int h = (ru >= 17), dd = ru - h * 17; qsh[h][lane][dd] = acc; }
                        else if (ru < 2 * D_) { int rr2 = ru - D_;     int h = (rr2 >= 17), dd = rr2 - h * 17; ksh[h][lane][dd] = acc; }
                        else                  { int rr2 = ru - 2 * D_; int h = (rr2 >= 17), dd = rr2 - h * 17; vsh[h][lane][dd] = acc; }
                    }
                }
            }
            __syncthreads();

            {
                int c = tid >> 7, hq = tid & 127;
                int h = hq >> 6, qi = hq & 63;
                float qv[17], acc[17];
                #pragma unroll
                for (int d = 0; d < 17; ++d) { qv[d] = qsh[h][qi][d]; acc[d] = 0.f; }
                float ssum = 0.f;
                int j0 = c * 16;
                #pragma unroll 4
                for (int jj = 0; jj < 16; ++jj) {
                    int j = j0 + jj;
                    const float4* kr = (const float4*)ksh[h][j];
                    const float4* vr = (const float4*)vsh[h][j];
                    float4 k0 = kr[0], k1 = kr[1], k2 = kr[2], k3 = kr[3];
                    float  k16 = ksh[h][j][16];
                    float4 v0 = vr[0], v1 = vr[1], v2 = vr[2], v3 = vr[3];
                    float  v16 = vsh[h][j][16];
                    float sE = qv[0]*k0.x + qv[2]*k0.z + qv[4]*k1.x + qv[6]*k1.z +
                               qv[8]*k2.x + qv[10]*k2.z + qv[12]*k3.x + qv[14]*k3.z;
                    float sO = qv[1]*k0.y + qv[3]*k0.w + qv[5]*k1.y + qv[7]*k1.w +
                               qv[9]*k2.y + qv[11]*k2.w + qv[13]*k3.y + qv[15]*k3.w;
                    float sc = sE + sO + qv[16]*k16;
                    float e = __expf(sc * rs17);
                    ssum += e;
                    acc[0] += e*v0.x;  acc[1] += e*v0.y;  acc[2] += e*v0.z;  acc[3] += e*v0.w;
                    acc[4] += e*v1.x;  acc[5] += e*v1.y;  acc[6] += e*v1.z;  acc[7] += e*v1.w;
                    acc[8] += e*v2.x;  acc[9] += e*v2.y;  acc[10] += e*v2.z; acc[11] += e*v2.w;
                    acc[12] += e*v3.x; acc[13] += e*v3.y; acc[14] += e*v3.z; acc[15] += e*v3.w;
                    acc[16] += e*v16;
                }
                #pragma unroll
                for (int d = 0; d < 17; ++d) pacc[c][hq][d] = acc[d];
                pacc[c][hq][17] = ssum;
            }
            __syncthreads();

            if (tid < 128) {
                int h = tid >> 6, qi = tid & 63;
                int off = h * 17;
                float ssum = pacc[0][tid][17] + pacc[1][tid][17] +
                             pacc[2][tid][17] + pacc[3][tid][17];
                float inv = 1.f / ssum;
                #pragma unroll
                for (int d = 0; d < 17; ++d)
                    att[qi][off + d] = (pacc[0][tid][d] + pacc[1][tid][d] +
                                        pacc[2][tid][d] + pacc[3][tid][d]) * inv;
            }
            __syncthreads();

            {
                v2f ar2[17];
                #pragma unroll
                for (int d2 = 0; d2 < 17; ++d2) {
                    v2f t; t.x = att[lane][2 * d2]; t.y = att[lane][2 * d2 + 1];
                    ar2[d2] = t;
                }
                const float* Wo = out_w + l * D_ * D_;
                const float* Bo = out_b + l * D_;
                #pragma unroll
                for (int rb = 0; rb < 5; ++rb) {
                    int d = wv_ + (rb << 3);
                    if (d < D_) {
                        int du = __builtin_amdgcn_readfirstlane(d);
                        const v2f* w2 = (const v2f*)(Wo + du * D_);
                        v2f a2; a2.x = Bo[du]; a2.y = 0.f;
                        #pragma unroll
                        for (int d2 = 0; d2 < 17; ++d2)
                            a2 = __builtin_elementwise_fma(ar2[d2], w2[d2], a2);
                        tmp[lane][du] = xs[lane][du] + a2.x + a2.y;
                    }
                }
            }
            __syncthreads();

            {
                int row = tid >> 3, sub = tid & 7;
                float s = 0.f, sq = 0.f;
                #pragma unroll
                for (int d = sub; d < D_; d += 8) { float t = tmp[row][d]; s += t; sq = fmaf(t, t, sq); }
                #pragma unroll
                for (int m = 1; m < 8; m <<= 1) { s += __shfl_xor(s, m, 8); sq += __shfl_xor(sq, m, 8); }
                float mu = s * (1.0f / D_);
                float var = fmaf(sq, 1.0f / D_, -mu * mu);
                float rstd = rsqrtf(var + 1e-5f);
                #pragma unroll
                for (int d = sub; d < D_; d += 8)
                    xs[row][d] = (tmp[row][d] - mu) * rstd * ln1_w[l * D_ + d] + ln1_b[l * D_ + d];
            }
            __syncthreads();

            if (wv_ < 4) {
                int fu = __builtin_amdgcn_readfirstlane(wv_);
                const v2f* w2 = (const v2f*)(lin1_w + l * FF_ * D_ + fu * D_);
                v2f a2; a2.x = lin1_b[l * FF_ + fu]; a2.y = 0.f;
                #pragma unroll
                for (int d2 = 0; d2 < 17; ++d2) {
                    v2f t; t.x = xs[lane][2 * d2]; t.y = xs[lane][2 * d2 + 1];
                    a2 = __builtin_elementwise_fma(t, w2[d2], a2);
                }
                ffh[lane][fu] = fmaxf(a2.x + a2.y, 0.f);
            }
            __syncthreads();

            {
                float h0 = ffh[lane][0], h1 = ffh[lane][1],
                      h2 = ffh[lane][2], h3 = ffh[lane][3];
                const float* W2 = lin2_w + l * D_ * FF_;
                const float* B2 = lin2_b + l * D_;
                #pragma unroll
                for (int rb = 0; rb < 5; ++rb) {
                    int d = wv_ + (rb << 3);
                    if (d < D_) {
                        int du = __builtin_amdgcn_readfirstlane(d);
                        const float* wrow = W2 + du * FF_;
                        float acc = fmaf(h0, wrow[0], fmaf(h1, wrow[1],
                                    fmaf(h2, wrow[2], fmaf(h3, wrow[3], B2[du]))));
                        tmp[lane][du] = xs[lane][du] + acc;
                    }
                }
            }
            __syncthreads();

            {
                int row = tid >> 3, sub = tid & 7;
                float s = 0.f, sq = 0.f;
                #pragma unroll
                for (int d = sub; d < D_; d += 8) { float t = tmp[row][d]; s += t; sq = fmaf(t, t, sq); }
                #pragma unroll
                for (int m = 1; m < 8; m <<= 1) { s += __shfl_xor(s, m, 8); sq += __shfl_xor(sq, m, 8); }
                float mu = s * (1.0f / D_);
                float var = fmaf(sq, 1.0f / D_, -mu * mu);
                float rstd = rsqrtf(var + 1e-5f);
                #pragma unroll
                for (int d = sub; d < D_; d += 8)
                    xs[row][d] = (tmp[row][d] - mu) * rstd * ln2_w[l * D_ + d] + ln2_b[l * D_ + d];
            }
            __syncthreads();
        }

        {
            int row = tid >> 3, sub = tid & 7;
            float s = 0.f, sq = 0.f;
            #pragma unroll
            for (int d = sub; d < D_; d += 8) { float t = xs[row][d]; s += t; sq = fmaf(t, t, sq); }
            #pragma unroll
            for (int m = 1; m < 8; m <<= 1) { s += __shfl_xor(s, m, 8); sq += __shfl_xor(sq, m, 8); }
            float mu = s * (1.0f / D_);
            float var = fmaf(sq, 1.0f / D_, -mu * mu);
            float rstd = rsqrtf(var + 1e-5f);
            #pragma unroll
            for (int d = sub; d < D_; d += 8)
                tmp[row][d] = (xs[row][d] - mu) * rstd * norm_w[d] + norm_b[d];
        }
        __syncthreads();

        if (wv_ < 3) {
            int ru = __builtin_amdgcn_readfirstlane(wv_);
            const v2f* w2 = (const v2f*)(eo_w + ru * D_);
            v2f a2; a2.x = eo_b[ru]; a2.y = 0.f;
            #pragma unroll
            for (int d2 = 0; d2 < 17; ++d2) {
                v2f t; t.x = tmp[lane][2 * d2]; t.y = tmp[lane][2 * d2 + 1];
                a2 = __builtin_elementwise_fma(t, w2[d2], a2);
            }
            mem[(b * S_ + lane) * DD_ + ru] = a2.x + a2.y;
        }

        if (tid < S_) {
            out[(b * S_ + tid) * 5 + 3] = src[(b * S_ + tid) * U_ + (U_ - 2)];
            out[(b * S_ + tid) * 5 + 4] = src[(b * S_ + tid) * U_ + (U_ - 1)];
        }

        // ---- publish: all mem writes done -> release signal
        __syncthreads();
        if (tid == 0) {
            __threadfence();
            __hip_atomic_fetch_add(&g_flagA, 1, __ATOMIC_RELEASE, __HIP_MEMORY_SCOPE_AGENT);
        }
        return;
    }

    // ======================= DECODER (exact R24 body) =======================
    if (tid >= 64) return;
    const int b = blockIdx.x - 64;
    const int lane = tid;
    const float LOG2E = 1.4426950408889634f;
    const float rs3 = 0.5773502691896258f;
    const float QS = rs3 * LOG2E;

    // ---- mem-INDEPENDENT prologue (overlaps encoder execution) ----
    float Wsq[NL_][6][3], Bsq[NL_][6];
    float Wvp[NL_][3][3], Bvp[NL_][3];
    float Bso[NL_][3];
    float N1w[NL_][3], N1bF[NL_][3];
    float N2w[NL_][3], N2bF[NL_][3];
    float wcu[NL_][3];
    float swcu[NL_];
    float cbb[NL_];
    float cvp[NL_][3];
    float W1N[NL_][4][3], b1n[NL_][4];
    float W2r[NL_][3][4];
    float N3w[NL_][3], N3b[NL_][3];

    #pragma unroll
    for (int l = 0; l < NL_; ++l) {
        #pragma unroll
        for (int r = 0; r < 6; ++r) {
            float sc = (r < 3) ? QS : 1.0f;
            Bsq[l][r] = sa_qkv_b[l * 9 + r] * sc;
            #pragma unroll
            for (int c = 0; c < 3; ++c) Wsq[l][r][c] = sa_qkv_w[l * 27 + r * 3 + c] * sc;
        }
        #pragma unroll
        for (int r = 0; r < 3; ++r) {
            float w0 = sa_out_w[l * 9 + r * 3 + 0];
            float w1 = sa_out_w[l * 9 + r * 3 + 1];
            float w2 = sa_out_w[l * 9 + r * 3 + 2];
            Bvp[l][r] = w0 * sa_qkv_b[l * 9 + 6] + w1 * sa_qkv_b[l * 9 + 7] + w2 * sa_qkv_b[l * 9 + 8];
            #pragma unroll
            for (int c = 0; c < 3; ++c)
                Wvp[l][r][c] = w0 * sa_qkv_w[l * 27 + 6 * 3 + c] +
                               w1 * sa_qkv_w[l * 27 + 7 * 3 + c] +
                               w2 * sa_qkv_w[l * 27 + 8 * 3 + c];
        }
        #pragma unroll
        for (int r = 0; r < 3; ++r) {
            Bso[l][r]  = sa_out_b[l * 3 + r];
            N1w[l][r]  = gln1_w[l * 3 + r];
            N1bF[l][r] = gln1_b[l * 3 + r] + ca_out_b[l * 3 + r];
            N2w[l][r]  = gln2_w[l * 3 + r];
            N2bF[l][r] = gln2_b[l * 3 + r] + l2_b[l * 3 + r];
            N3w[l][r]  = gln3_w[l * 3 + r];
            N3b[l][r]  = gln3_b[l * 3 + r];
        }
        #pragma unroll
        for (int j = 0; j < 4; ++j) {
            #pragma unroll
            for (int c = 0; c < 3; ++c)
                W1N[l][j][c] = l1_w[l * 12 + j * 3 + c] * gln2_w[l * 3 + c];
            b1n[l][j] = l1_w[l * 12 + j * 3 + 0] * gln2_b[l * 3 + 0] +
                        l1_w[l * 12 + j * 3 + 1] * gln2_b[l * 3 + 1] +
                        l1_w[l * 12 + j * 3 + 2] * gln2_b[l * 3 + 2] + l1_b[l * 4 + j];
        }
        #pragma unroll
        for (int r = 0; r < 3; ++r)
            #pragma unroll
            for (int j = 0; j < 4; ++j)
                W2r[l][r][j] = l2_w[l * 12 + r * 4 + j];
    }

    // ---- acquire-spin until all 64 encoder blocks have published mem ----
    while (__hip_atomic_load(&g_flagA, __ATOMIC_ACQUIRE, __HIP_MEMORY_SCOPE_AGENT) < 64) {
        __builtin_amdgcn_s_sleep(8);
    }
    asm volatile("" ::: "memory");

    // ---- mem-DEPENDENT cross-attn K/V + query-side folds (LN1 folded in) ----
    float m0 = mem[(b * S_ + lane) * DD_ + 0];
    float m1 = mem[(b * S_ + lane) * DD_ + 1];
    float m2 = mem[(b * S_ + lane) * DD_ + 2];

    #pragma unroll
    for (int l = 0; l < NL_; ++l) {
        float ck[3], cv[3], cuv[3];
        #pragma unroll
        for (int r = 0; r < 3; ++r) {
            ck[r] = ca_qkv_w[l * 27 + (3 + r) * 3 + 0] * m0 +
                    ca_qkv_w[l * 27 + (3 + r) * 3 + 1] * m1 +
                    ca_qkv_w[l * 27 + (3 + r) * 3 + 2] * m2 + ca_qkv_b[l * 9 + 3 + r];
            cv[r] = ca_qkv_w[l * 27 + (6 + r) * 3 + 0] * m0 +
                    ca_qkv_w[l * 27 + (6 + r) * 3 + 1] * m1 +
                    ca_qkv_w[l * 27 + (6 + r) * 3 + 2] * m2 + ca_qkv_b[l * 9 + 6 + r];
        }
        #pragma unroll
        for (int s = 0; s < 3; ++s)
            cuv[s] = QS * (ca_qkv_w[l * 27 + 0 + s] * ck[0] +
                           ca_qkv_w[l * 27 + 3 + s] * ck[1] +
                           ca_qkv_w[l * 27 + 6 + s] * ck[2]);
        float cbv = QS * (ca_qkv_b[l * 9 + 0] * ck[0] +
                          ca_qkv_b[l * 9 + 1] * ck[1] +
                          ca_qkv_b[l * 9 + 2] * ck[2]);
        #pragma unroll
        for (int r = 0; r < 3; ++r)
            cvp[l][r] = ca_out_w[l * 9 + r * 3 + 0] * cv[0] +
                        ca_out_w[l * 9 + r * 3 + 1] * cv[1] +
                        ca_out_w[l * 9 + r * 3 + 2] * cv[2];
        #pragma unroll
        for (int r = 0; r < 3; ++r) wcu[l][r] = cuv[r] * N1w[l][r];
        swcu[l] = wcu[l][0] + wcu[l][1] + wcu[l][2];
        cbb[l]  = cbv + cuv[0] * gln1_b[l * 3 + 0] + cuv[1] * gln1_b[l * 3 + 1]
                      + cuv[2] * gln1_b[l * 3 + 2];
    }

    // ---- pin the chain-critical persistent set (all scalar floats)
    #pragma unroll
    for (int l = 0; l < NL_; ++l) {
        #pragma unroll
        for (int r = 0; r < 6; ++r) {
            PIN(Bsq[l][r]);
            #pragma unroll
            for (int c = 0; c < 3; ++c) PIN(Wsq[l][r][c]);
        }
        PIN(swcu[l]); PIN(cbb[l]);
        #pragma unroll
        for (int r = 0; r < 3; ++r) {
            PIN(Bvp[l][r]); PIN(Bso[l][r]);
            PIN(N1w[l][r]); PIN(N1bF[l][r]); PIN(N2w[l][r]); PIN(N2bF[l][r]);
            PIN(N3w[l][r]); PIN(N3b[l][r]);
            PIN(wcu[l][r]); PIN(cvp[l][r]);
            #pragma unroll
            for (int c = 0; c < 3; ++c) PIN(Wvp[l][r][c]);
            #pragma unroll
            for (int j = 0; j < 4; ++j) PIN(W2r[l][r][j]);
        }
        #pragma unroll
        for (int j = 0; j < 4; ++j) {
            PIN(b1n[l][j]);
            #pragma unroll
            for (int c = 0; c < 3; ++c) PIN(W1N[l][j][c]);
        }
    }

    float sk[NL_][3] = {{0.f}}, sv[NL_][3] = {{0.f}};

    if (lane < 3) out[(b * S_ + 0) * 5 + lane] = 0.f;

    float y0 = 0.f, y1 = 0.f, y2 = 0.f;

    auto run_range = [&](int ibeg, int iend, auto nstc) {
        constexpr int NST = decltype(nstc)::value;
        constexpr int RL = (NST == 4) ? 15 : (NST == 5) ? 31 : 63;
        for (int i = ibeg; i < iend; ++i) {
            float msa = (lane <= i) ? 0.f : -1.0e30f;
            bool isme = (lane == i);
            #pragma unroll
            for (int l = 0; l < NL_; ++l) {
                float q[3], kn[3], vp[3];
                #pragma unroll
                for (int r = 0; r < 3; ++r) {
                    kn[r] = fmaf(Wsq[l][3 + r][0], y0, fmaf(Wsq[l][3 + r][1], y1, fmaf(Wsq[l][3 + r][2], y2, Bsq[l][3 + r])));
                    q[r]  = fmaf(Wsq[l][r][0], y0, fmaf(Wsq[l][r][1], y1, fmaf(Wsq[l][r][2], y2, Bsq[l][r])));
                    vp[r] = fmaf(Wvp[l][r][0], y0, fmaf(Wvp[l][r][1], y1, fmaf(Wvp[l][r][2], y2, Bvp[l][r])));
                }
                if (isme) {
                    #pragma unroll
                    for (int r = 0; r < 3; ++r) { sk[l][r] = kn[r]; sv[l][r] = vp[r]; }
                }
                float sc = fmaf(q[0], sk[l][0], fmaf(q[1], sk[l][1], fmaf(q[2], sk[l][2], msa)));
                float e = __builtin_amdgcn_exp2f(sc);
                float se = e;
                float sa0 = e * sv[l][0];
                float sa1 = e * sv[l][1];
                float sa2 = e * sv[l][2];
                red16_4(se, sa0, sa1, sa2);
                if constexpr (NST >= 5) dpp4<0x142>(se, sa0, sa1, sa2);
                if constexpr (NST >= 6) dpp4<0x143>(se, sa0, sa1, sa2);
                float es = rlane<RL>(se);
                float S0 = rlane<RL>(sa0), S1 = rlane<RL>(sa1), S2 = rlane<RL>(sa2);
                float yb0 = y0 + Bso[l][0], yb1 = y1 + Bso[l][1], yb2 = y2 + Bso[l][2];
                float z0 = fmaf(yb0, es, S0), z1 = fmaf(yb1, es, S1), z2v = fmaf(yb2, es, S2);
                float ee = es * es;

                float s1m = (z0 + z1) + z2v;
                float mu = s1m * (1.0f / 3.0f);
                float zw = fmaf(z0, wcu[l][0], fmaf(z1, wcu[l][1], z2v * wcu[l][2]));
                float inner = fmaf(-mu, swcu[l], zw);
                float s2m = fmaf(z0, z0, fmaf(z1, z1, z2v * z2v));
                float vpe = fmaf(s2m, (1.0f / 3.0f), fmaf(-mu, mu, 1e-5f * ee));
                float rstd1 = __builtin_amdgcn_rsqf(vpe);
                float sc2 = fmaf(rstd1, inner, cbb[l]);
                float e2 = __builtin_amdgcn_exp2f(sc2);
                float ce = e2;
                float ca0 = e2 * cvp[l][0];
                float ca1 = e2 * cvp[l][1];
                float ca2 = e2 * cvp[l][2];
                red16_4(ce, ca0, ca1, ca2);
                dpp4<0x142>(ce, ca0, ca1, ca2);
                dpp4<0x143>(ce, ca0, ca1, ca2);
                float yc0 = fmaf(z0 - mu, rstd1 * N1w[l][0], N1bF[l][0]);
                float yc1 = fmaf(z1 - mu, rstd1 * N1w[l][1], N1bF[l][1]);
                float yc2 = fmaf(z2v - mu, rstd1 * N1w[l][2], N1bF[l][2]);
                float cs = rlane<63>(ce);
                float C0 = rlane<63>(ca0), C1 = rlane<63>(ca1), C2 = rlane<63>(ca2);
                float g0 = fmaf(yc0, cs, C0), g1 = fmaf(yc1, cs, C1), g2 = fmaf(yc2, cs, C2);
                float cee = cs * cs;

                float t1m = (g0 + g1) + g2;
                float mu2 = t1m * (1.0f / 3.0f);
                float c20 = g0 - mu2, c21 = g1 - mu2, c22 = g2 - mu2;
                float t2m = fmaf(g0, g0, fmaf(g1, g1, g2 * g2));
                float vpe2 = fmaf(t2m, (1.0f / 3.0f), fmaf(-mu2, mu2, 1e-5f * cee));
                float rstd2 = __builtin_amdgcn_rsqf(vpe2);
                float d0 = fmaf(W1N[l][0][0], c20, fmaf(W1N[l][0][1], c21, W1N[l][0][2] * c22));
                float d1 = fmaf(W1N[l][1][0], c20, fmaf(W1N[l][1][1], c21, W1N[l][1][2] * c22));
                float d2 = fmaf(W1N[l][2][0], c20, fmaf(W1N[l][2][1], c21, W1N[l][2][2] * c22));
                float d3 = fmaf(W1N[l][3][0], c20, fmaf(W1N[l][3][1], c21, W1N[l][3][2] * c22));
                float h0 = fmaxf(fmaf(rstd2, d0, b1n[l][0]), 0.f);
                float h1 = fmaxf(fmaf(rstd2, d1, b1n[l][1]), 0.f);
                float h2 = fmaxf(fmaf(rstd2, d2, b1n[l][2]), 0.f);
                float h3 = fmaxf(fmaf(rstd2, d3, b1n[l][3]), 0.f);
                float yf0 = fmaf(c20, rstd2 * N2w[l][0], N2bF[l][0]);
                float yf1 = fmaf(c21, rstd2 * N2w[l][1], N2bF[l][1]);
                float yf2 = fmaf(c22, rstd2 * N2w[l][2], N2bF[l][2]);
                float f0 = fmaf(W2r[l][0][0], h0, fmaf(W2r[l][0][1], h1, fmaf(W2r[l][0][2], h2, fmaf(W2r[l][0][3], h3, yf0))));
                float f1 = fmaf(W2r[l][1][0], h0, fmaf(W2r[l][1][1], h1, fmaf(W2r[l][1][2], h2, fmaf(W2r[l][1][3], h3, yf1))));
                float f2 = fmaf(W2r[l][2][0], h0, fmaf(W2r[l][2][1], h1, fmaf(W2r[l][2][2], h2, fmaf(W2r[l][2][3], h3, yf2))));
                ln3e(f0, f1, f2,
                     N3w[l][0], N3w[l][1], N3w[l][2], N3b[l][0], N3b[l][1], N3b[l][2],
                     y0, y1, y2);
            }
            if (lane == 0) {
                out[(b * S_ + i + 1) * 5 + 0] = y0;
                out[(b * S_ + i + 1) * 5 + 1] = y1;
                out[(b * S_ + i + 1) * 5 + 2] = y2;
            }
        }
    };

    run_range(0, 15, IC<4>{});
    run_range(15, 31, IC<5>{});
    run_range(31, S_ - 1, IC<6>{});

    // ---- self-resetting flag protocol: last dec block zeroes both flags
    if (lane == 0) {
        int old = __hip_atomic_fetch_add(&g_flagB, 1, __ATOMIC_ACQ_REL, __HIP_MEMORY_SCOPE_AGENT);
        if (old == 63) {
            __hip_atomic_store(&g_flagA, 0, __ATOMIC_RELAXED, __HIP_MEMORY_SCOPE_AGENT);
            __hip_atomic_store(&g_flagB, 0, __ATOMIC_RELAXED, __HIP_MEMORY_SCOPE_AGENT);
        }
    }
}

// ---------------------------------------------------------------------------
extern "C" void kernel_launch(void* const* d_in, const int* in_sizes, int n_in,
                              void* d_out, int out_size, void* d_ws, size_t ws_size,
                              hipStream_t stream) {
    const float* src  = (const float*)d_in[0];
    const float* wemb = (const float*)d_in[1];
    const float* semb = (const float*)d_in[2];

    float* mem = (float*)d_ws;           // [B,S,3] scratch
    float* out = (float*)d_out;          // [B,S,5]

    fused_kernel<<<128, 512, 0, stream>>>(
        src, wemb, semb,
        (const float*)d_in[3],  (const float*)d_in[4],
        (const float*)d_in[5],  (const float*)d_in[6],
        (const float*)d_in[7],  (const float*)d_in[8],
        (const float*)d_in[9],  (const float*)d_in[10],
        (const float*)d_in[11], (const float*)d_in[12],
        (const float*)d_in[13], (const float*)d_in[14],
        (const float*)d_in[15], (const float*)d_in[16],
        (const float*)d_in[17], (const float*)d_in[18],
        (const float*)d_in[19], (const float*)d_in[20],
        (const float*)d_in[21], (const float*)d_in[22],
        (const float*)d_in[23], (const float*)d_in[24],
        (const float*)d_in[25], (const float*)d_in[26],
        (const float*)d_in[27], (const float*)d_in[28],
        (const float*)d_in[29], (const float*)d_in[30],
        (const float*)d_in[31], (const float*)d_in[32],
        (const float*)d_in[33], (const float*)d_in[34],
        (const float*)d_in[35], (const float*)d_in[36],
        mem, out);
}

// Round 12
// 306.021 us; speedup vs baseline: 2.2651x; 2.2651x over previous
//
#include <hip/hip_runtime.h>
#include <math.h>

#define B_ 64
#define S_ 64
#define U_ 16
#define EMB_ 10
#define D_ 34
#define DD_ 3
#define FF_ 4
#define NL_ 4

typedef float v2f __attribute__((ext_vector_type(2)));

// ---------------------------------------------------------------------------
// Kernel A: encoder — EXACT R13 (measured best: total 336.2 µs, enc ~63.7).
// FROZEN.
// ---------------------------------------------------------------------------
__global__ __launch_bounds__(512) void enc_kernel(
    const float* __restrict__ src, const float* __restrict__ wemb,
    const float* __restrict__ semb,
    const float* __restrict__ qkv_w, const float* __restrict__ qkv_b,
    const float* __restrict__ out_w, const float* __restrict__ out_b,
    const float* __restrict__ ln1_w, const float* __restrict__ ln1_b,
    const float* __restrict__ lin1_w, const float* __restrict__ lin1_b,
    const float* __restrict__ lin2_w, const float* __restrict__ lin2_b,
    const float* __restrict__ ln2_w, const float* __restrict__ ln2_b,
    const float* __restrict__ norm_w, const float* __restrict__ norm_b,
    const float* __restrict__ eo_w, const float* __restrict__ eo_b,
    float* __restrict__ mem, float* __restrict__ out)
{
    const int b = blockIdx.x;
    const int tid = threadIdx.x;
    const int wv_ = tid >> 6;
    const int lane = tid & 63;

    __shared__ float xs[S_][D_ + 1];
    __shared__ float tmp[S_][D_ + 1];
    __shared__ float att[S_][D_ + 1];
    __shared__ __align__(16) float qsh[2][S_][21];
    __shared__ __align__(16) float ksh[2][S_][20];
    __shared__ __align__(16) float vsh[2][S_][20];
    __shared__ float ffh[S_][5];
    __shared__ float pacc[4][128][19];

    const float rs17 = 0.24253562503633297f;
    const float negln = -logf(10000.0f) / (float)D_;

    // ---- embed + positional encoding
    #pragma unroll
    for (int rr = 0; rr < 5; ++rr) {
        int idx = tid + rr * 512;
        if (idx < S_ * D_) {
            int pos = idx / D_, d = idx % D_;
            float v;
            if (d < U_ - 2) {
                v = src[(b * S_ + pos) * U_ + d];
            } else if (d < U_ - 2 + EMB_) {
                int wi = (int)src[(b * S_ + pos) * U_ + (U_ - 2)];
                v = wemb[wi * EMB_ + (d - (U_ - 2))];
            } else {
                int si = (int)src[(b * S_ + pos) * U_ + (U_ - 1)];
                v = semb[si * EMB_ + (d - (U_ - 2 + EMB_))];
            }
            int k = d >> 1;
            float div = __expf((float)(2 * k) * negln);
            float ang = (float)b * div;
            v += (d & 1) ? __cosf(ang) : __sinf(ang);
            xs[pos][d] = v;
        }
    }
    __syncthreads();

    for (int l = 0; l < NL_; ++l) {
        const float* Wq = qkv_w + l * 3 * D_ * D_;
        const float* Bq = qkv_b + l * 3 * D_;

        // ---- qkv: lane = pos; wave owns rows r = wv_ + 8k; pk_fma dot
        {
            v2f xr2[17];
            #pragma unroll
            for (int d2 = 0; d2 < 17; ++d2) {
                v2f t; t.x = xs[lane][2 * d2]; t.y = xs[lane][2 * d2 + 1];
                xr2[d2] = t;
            }
            #pragma unroll
            for (int rb = 0; rb < 13; ++rb) {
                int r = wv_ + (rb << 3);
                if (r < 3 * D_) {
                    int ru = __builtin_amdgcn_readfirstlane(r);
                    const v2f* w2 = (const v2f*)(Wq + ru * D_);
                    v2f a2; a2.x = Bq[ru]; a2.y = 0.f;
                    #pragma unroll
                    for (int d2 = 0; d2 < 17; ++d2)
                        a2 = __builtin_elementwise_fma(xr2[d2], w2[d2], a2);
                    float acc = a2.x + a2.y;
                    if (ru < D_)          { int h = (ru >= 17), dd = ru - h * 17; qsh[h][lane][dd] = acc; }
                    else if (ru < 2 * D_) { int rr2 = ru - D_;     int h = (rr2 >= 17), dd = rr2 - h * 17; ksh[h][lane][dd] = acc; }
                    else                  { int rr2 = ru - 2 * D_; int h = (rr2 >= 17), dd = rr2 - h * 17; vsh[h][lane][dd] = acc; }
                }
            }
        }
        __syncthreads();

        // ---- attention, 4-way key-parallel
        {
            int c = tid >> 7, hq = tid & 127;
            int h = hq >> 6, qi = hq & 63;
            float qv[17], acc[17];
            #pragma unroll
            for (int d = 0; d < 17; ++d) { qv[d] = qsh[h][qi][d]; acc[d] = 0.f; }
            float ssum = 0.f;
            int j0 = c * 16;
            #pragma unroll 4
            for (int jj = 0; jj < 16; ++jj) {
                int j = j0 + jj;
                const float4* kr = (const float4*)ksh[h][j];
                const float4* vr = (const float4*)vsh[h][j];
                float4 k0 = kr[0], k1 = kr[1], k2 = kr[2], k3 = kr[3];
                float  k16 = ksh[h][j][16];
                float4 v0 = vr[0], v1 = vr[1], v2 = vr[2], v3 = vr[3];
                float  v16 = vsh[h][j][16];
                float sE = qv[0]*k0.x + qv[2]*k0.z + qv[4]*k1.x + qv[6]*k1.z +
                           qv[8]*k2.x + qv[10]*k2.z + qv[12]*k3.x + qv[14]*k3.z;
                float sO = qv[1]*k0.y + qv[3]*k0.w + qv[5]*k1.y + qv[7]*k1.w +
                           qv[9]*k2.y + qv[11]*k2.w + qv[13]*k3.y + qv[15]*k3.w;
                float sc = sE + sO + qv[16]*k16;
                float e = __expf(sc * rs17);
                ssum += e;
                acc[0] += e*v0.x;  acc[1] += e*v0.y;  acc[2] += e*v0.z;  acc[3] += e*v0.w;
                acc[4] += e*v1.x;  acc[5] += e*v1.y;  acc[6] += e*v1.z;  acc[7] += e*v1.w;
                acc[8] += e*v2.x;  acc[9] += e*v2.y;  acc[10] += e*v2.z; acc[11] += e*v2.w;
                acc[12] += e*v3.x; acc[13] += e*v3.y; acc[14] += e*v3.z; acc[15] += e*v3.w;
                acc[16] += e*v16;
            }
            #pragma unroll
            for (int d = 0; d < 17; ++d) pacc[c][hq][d] = acc[d];
            pacc[c][hq][17] = ssum;
        }
        __syncthreads();

        if (tid < 128) {
            int h = tid >> 6, qi = tid & 63;
            int off = h * 17;
            float ssum = pacc[0][tid][17] + pacc[1][tid][17] +
                         pacc[2][tid][17] + pacc[3][tid][17];
            float inv = 1.f / ssum;
            #pragma unroll
            for (int d = 0; d < 17; ++d)
                att[qi][off + d] = (pacc[0][tid][d] + pacc[1][tid][d] +
                                    pacc[2][tid][d] + pacc[3][tid][d]) * inv;
        }
        __syncthreads();

        // ---- out proj + residual (pk_fma)
        {
            v2f ar2[17];
            #pragma unroll
            for (int d2 = 0; d2 < 17; ++d2) {
                v2f t; t.x = att[lane][2 * d2]; t.y = att[lane][2 * d2 + 1];
                ar2[d2] = t;
            }
            const float* Wo = out_w + l * D_ * D_;
            const float* Bo = out_b + l * D_;
            #pragma unroll
            for (int rb = 0; rb < 5; ++rb) {
                int d = wv_ + (rb << 3);
                if (d < D_) {
                    int du = __builtin_amdgcn_readfirstlane(d);
                    const v2f* w2 = (const v2f*)(Wo + du * D_);
                    v2f a2; a2.x = Bo[du]; a2.y = 0.f;
                    #pragma unroll
                    for (int d2 = 0; d2 < 17; ++d2)
                        a2 = __builtin_elementwise_fma(ar2[d2], w2[d2], a2);
                    tmp[lane][du] = xs[lane][du] + a2.x + a2.y;
                }
            }
        }
        __syncthreads();

        // ---- LN1: 8 threads/row (all 512 active), shfl_xor(8) reduction
        {
            int row = tid >> 3, sub = tid & 7;
            float s = 0.f, sq = 0.f;
            #pragma unroll
            for (int d = sub; d < D_; d += 8) { float t = tmp[row][d]; s += t; sq = fmaf(t, t, sq); }
            #pragma unroll
            for (int m = 1; m < 8; m <<= 1) { s += __shfl_xor(s, m, 8); sq += __shfl_xor(sq, m, 8); }
            float mu = s * (1.0f / D_);
            float var = fmaf(sq, 1.0f / D_, -mu * mu);
            float rstd = rsqrtf(var + 1e-5f);
            #pragma unroll
            for (int d = sub; d < D_; d += 8)
                xs[row][d] = (tmp[row][d] - mu) * rstd * ln1_w[l * D_ + d] + ln1_b[l * D_ + d];
        }
        __syncthreads();

        // ---- FF1 (34 -> 4, relu): waves 0..3 (pk_fma)
        if (wv_ < 4) {
            int fu = __builtin_amdgcn_readfirstlane(wv_);
            const v2f* w2 = (const v2f*)(lin1_w + l * FF_ * D_ + fu * D_);
            v2f a2; a2.x = lin1_b[l * FF_ + fu]; a2.y = 0.f;
            #pragma unroll
            for (int d2 = 0; d2 < 17; ++d2) {
                v2f t; t.x = xs[lane][2 * d2]; t.y = xs[lane][2 * d2 + 1];
                a2 = __builtin_elementwise_fma(t, w2[d2], a2);
            }
            ffh[lane][fu] = fmaxf(a2.x + a2.y, 0.f);
        }
        __syncthreads();

        // ---- FF2 (4 -> 34) + residual
        {
            float h0 = ffh[lane][0], h1 = ffh[lane][1],
                  h2 = ffh[lane][2], h3 = ffh[lane][3];
            const float* W2 = lin2_w + l * D_ * FF_;
            const float* B2 = lin2_b + l * D_;
            #pragma unroll
            for (int rb = 0; rb < 5; ++rb) {
                int d = wv_ + (rb << 3);
                if (d < D_) {
                    int du = __builtin_amdgcn_readfirstlane(d);
                    const float* wrow = W2 + du * FF_;
                    float acc = fmaf(h0, wrow[0], fmaf(h1, wrow[1],
                                fmaf(h2, wrow[2], fmaf(h3, wrow[3], B2[du]))));
                    tmp[lane][du] = xs[lane][du] + acc;
                }
            }
        }
        __syncthreads();

        // ---- LN2: 8 threads/row
        {
            int row = tid >> 3, sub = tid & 7;
            float s = 0.f, sq = 0.f;
            #pragma unroll
            for (int d = sub; d < D_; d += 8) { float t = tmp[row][d]; s += t; sq = fmaf(t, t, sq); }
            #pragma unroll
            for (int m = 1; m < 8; m <<= 1) { s += __shfl_xor(s, m, 8); sq += __shfl_xor(sq, m, 8); }
            float mu = s * (1.0f / D_);
            float var = fmaf(sq, 1.0f / D_, -mu * mu);
            float rstd = rsqrtf(var + 1e-5f);
            #pragma unroll
            for (int d = sub; d < D_; d += 8)
                xs[row][d] = (tmp[row][d] - mu) * rstd * ln2_w[l * D_ + d] + ln2_b[l * D_ + d];
        }
        __syncthreads();
    }

    // ---- final LayerNorm: 8 threads/row
    {
        int row = tid >> 3, sub = tid & 7;
        float s = 0.f, sq = 0.f;
        #pragma unroll
        for (int d = sub; d < D_; d += 8) { float t = xs[row][d]; s += t; sq = fmaf(t, t, sq); }
        #pragma unroll
        for (int m = 1; m < 8; m <<= 1) { s += __shfl_xor(s, m, 8); sq += __shfl_xor(sq, m, 8); }
        float mu = s * (1.0f / D_);
        float var = fmaf(sq, 1.0f / D_, -mu * mu);
        float rstd = rsqrtf(var + 1e-5f);
        #pragma unroll
        for (int d = sub; d < D_; d += 8)
            tmp[row][d] = (xs[row][d] - mu) * rstd * norm_w[d] + norm_b[d];
    }
    __syncthreads();

    // ---- memory = x @ eo_w.T + eo_b : waves 0..2 (pk_fma), reads tmp
    if (wv_ < 3) {
        int ru = __builtin_amdgcn_readfirstlane(wv_);
        const v2f* w2 = (const v2f*)(eo_w + ru * D_);
        v2f a2; a2.x = eo_b[ru]; a2.y = 0.f;
        #pragma unroll
        for (int d2 = 0; d2 < 17; ++d2) {
            v2f t; t.x = tmp[lane][2 * d2]; t.y = tmp[lane][2 * d2 + 1];
            a2 = __builtin_elementwise_fma(t, w2[d2], a2);
        }
        mem[(b * S_ + lane) * DD_ + ru] = a2.x + a2.y;
    }

    if (tid < S_) {
        out[(b * S_ + tid) * 5 + 3] = src[(b * S_ + tid) * U_ + (U_ - 2)];
        out[(b * S_ + tid) * 5 + 4] = src[(b * S_ + tid) * U_ + (U_ - 1)];
    }
}

// ---------------------------------------------------------------------------
// Kernel B: decoder — FINAL = R23 exactly (best graded total: 305.0 µs).
// Carries every validated win: Wvp fold (vp=(Wso·Wv)y+Wso·bv), LN1->CA-score
// fold, LN2->FF1 fold, bias folds (N1bF=gln1_b+Bco, N2bF=gln2_b+l2_b),
// scale-invariant LN (no rcp on chain), interleaved 4-value DPP reductions,
// 3-region adaptive reduction depth, LDS-amortized FF-tail stage.
// R25's single-kernel fusion failed (shared 128-VGPR budget -> decoder weight
// set spilled, 5.9 MB scratch traffic); two-kernel form restored.
// ---------------------------------------------------------------------------
#define PIN(x) asm volatile("" : "+v"(x))

template <int N> struct IC { static constexpr int value = N; };

template <int CTRL>
__device__ __forceinline__ void dpp4(float& a, float& b, float& c, float& d) {
    int ta = __builtin_amdgcn_update_dpp(0, __float_as_int(a), CTRL, 0xf, 0xf, true);
    int tb = __builtin_amdgcn_update_dpp(0, __float_as_int(b), CTRL, 0xf, 0xf, true);
    int tc = __builtin_amdgcn_update_dpp(0, __float_as_int(c), CTRL, 0xf, 0xf, true);
    int td = __builtin_amdgcn_update_dpp(0, __float_as_int(d), CTRL, 0xf, 0xf, true);
    a += __int_as_float(ta);
    b += __int_as_float(tb);
    c += __int_as_float(tc);
    d += __int_as_float(td);
}

__device__ __forceinline__ void red16_4(float& a, float& b, float& c, float& d) {
    dpp4<0x111>(a, b, c, d);
    dpp4<0x112>(a, b, c, d);
    dpp4<0x114>(a, b, c, d);
    dpp4<0x118>(a, b, c, d);   // lane 15 of each row = row sum
}

template <int L>
__device__ __forceinline__ float rlane(float v) {
    return __int_as_float(__builtin_amdgcn_readlane(__float_as_int(v), L));
}

__device__ __forceinline__ void ln3e(float z0, float z1, float z2,
                                     float w0, float w1, float w2,
                                     float b0, float b1, float b2,
                                     float& o0, float& o1, float& o2) {
    float s1 = (z0 + z1) + z2;
    float s2 = fmaf(z0, z0, fmaf(z1, z1, z2 * z2));
    float mu = s1 * (1.0f / 3.0f);
    float vpe = fmaf(s2, (1.0f / 3.0f), fmaf(-mu, mu, 1e-5f));
    float rstd = __builtin_amdgcn_rsqf(vpe);
    o0 = fmaf(z0 - mu, rstd * w0, b0);
    o1 = fmaf(z1 - mu, rstd * w1, b1);
    o2 = fmaf(z2 - mu, rstd * w2, b2);
}

__global__ __launch_bounds__(64, 1) void dec_kernel(
    const float* __restrict__ mem,
    const float* __restrict__ sa_qkv_w, const float* __restrict__ sa_qkv_b,
    const float* __restrict__ sa_out_w, const float* __restrict__ sa_out_b,
    const float* __restrict__ gln1_w, const float* __restrict__ gln1_b,
    const float* __restrict__ ca_qkv_w, const float* __restrict__ ca_qkv_b,
    const float* __restrict__ ca_out_w, const float* __restrict__ ca_out_b,
    const float* __restrict__ gln2_w, const float* __restrict__ gln2_b,
    const float* __restrict__ l1_w, const float* __restrict__ l1_b,
    const float* __restrict__ l2_w, const float* __restrict__ l2_b,
    const float* __restrict__ gln3_w, const float* __restrict__ gln3_b,
    float* __restrict__ out)
{
    const int b = blockIdx.x;
    const int lane = threadIdx.x;
    const float LOG2E = 1.4426950408889634f;
    const float rs3 = 0.5773502691896258f;
    const float QS = rs3 * LOG2E;   // score scale folded into weights, exp->exp2

    // ---- FF-tail weight stage: W1N = W1 ∘ N2w, b1n = W1·N2b + b1 (LN2 fold)
    __shared__ __align__(16) float fst[NL_][40];
    for (int t = lane; t < NL_ * 40; t += 64) {
        int l = t / 40, s = t % 40;
        float v = 0.f;
        if      (s < 12) v = l1_w[l * 12 + s] * gln2_w[l * 3 + (s % 3)];
        else if (s < 16) {
            int j = s - 12;
            v = l1_w[l * 12 + j * 3 + 0] * gln2_b[l * 3 + 0] +
                l1_w[l * 12 + j * 3 + 1] * gln2_b[l * 3 + 1] +
                l1_w[l * 12 + j * 3 + 2] * gln2_b[l * 3 + 2] + l1_b[l * 4 + j];
        }
        else if (s < 28) v = l2_w[l * 12 + (s - 16)];
        else if (s < 31) v = 0.f;                        // l2_b folded into N2bF
        else if (s < 34) v = gln3_w[l * 3 + (s - 31)];
        else if (s < 37) v = gln3_b[l * 3 + (s - 34)];
        fst[l][s] = v;
    }
    __syncthreads();

    // ---- persistent pinned weights (all scalar)
    float Wsq[NL_][6][3], Bsq[NL_][6];      // q (QS-scaled) + k rows
    float Wvp[NL_][3][3], Bvp[NL_][3];      // folded value path
    float Bso[NL_][3];
    float N1w[NL_][3], N1bF[NL_][3];        // N1bF = gln1_b + Bco
    float N2w[NL_][3], N2bF[NL_][3];        // N2bF = gln2_b + l2_b
    float wcu[NL_][3];
    float swcu[NL_];
    float cbb[NL_];
    float cvp[NL_][3];

    #pragma unroll
    for (int l = 0; l < NL_; ++l) {
        #pragma unroll
        for (int r = 0; r < 6; ++r) {
            float sc = (r < 3) ? QS : 1.0f;
            Bsq[l][r] = sa_qkv_b[l * 9 + r] * sc;
            #pragma unroll
            for (int c = 0; c < 3; ++c) Wsq[l][r][c] = sa_qkv_w[l * 27 + r * 3 + c] * sc;
        }
        // Wvp = Wso·Wv, Bvp = Wso·Bv
        #pragma unroll
        for (int r = 0; r < 3; ++r) {
            float w0 = sa_out_w[l * 9 + r * 3 + 0];
            float w1 = sa_out_w[l * 9 + r * 3 + 1];
            float w2 = sa_out_w[l * 9 + r * 3 + 2];
            Bvp[l][r] = w0 * sa_qkv_b[l * 9 + 6] + w1 * sa_qkv_b[l * 9 + 7] + w2 * sa_qkv_b[l * 9 + 8];
            #pragma unroll
            for (int c = 0; c < 3; ++c)
                Wvp[l][r][c] = w0 * sa_qkv_w[l * 27 + 6 * 3 + c] +
                               w1 * sa_qkv_w[l * 27 + 7 * 3 + c] +
                               w2 * sa_qkv_w[l * 27 + 8 * 3 + c];
        }
        #pragma unroll
        for (int r = 0; r < 3; ++r) {
            Bso[l][r]  = sa_out_b[l * 3 + r];
            N1w[l][r]  = gln1_w[l * 3 + r];
            N1bF[l][r] = gln1_b[l * 3 + r] + ca_out_b[l * 3 + r];
            N2w[l][r]  = gln2_w[l * 3 + r];
            N2bF[l][r] = gln2_b[l * 3 + r] + l2_b[l * 3 + r];
        }
    }

    // ---- cross-attn K/V per lane + query-side folds (LN1 folded in)
    float m0 = mem[(b * S_ + lane) * DD_ + 0];
    float m1 = mem[(b * S_ + lane) * DD_ + 1];
    float m2 = mem[(b * S_ + lane) * DD_ + 2];

    #pragma unroll
    for (int l = 0; l < NL_; ++l) {
        float ck[3], cv[3], cuv[3];
        #pragma unroll
        for (int r = 0; r < 3; ++r) {
            ck[r] = ca_qkv_w[l * 27 + (3 + r) * 3 + 0] * m0 +
                    ca_qkv_w[l * 27 + (3 + r) * 3 + 1] * m1 +
                    ca_qkv_w[l * 27 + (3 + r) * 3 + 2] * m2 + ca_qkv_b[l * 9 + 3 + r];
            cv[r] = ca_qkv_w[l * 27 + (6 + r) * 3 + 0] * m0 +
                    ca_qkv_w[l * 27 + (6 + r) * 3 + 1] * m1 +
                    ca_qkv_w[l * 27 + (6 + r) * 3 + 2] * m2 + ca_qkv_b[l * 9 + 6 + r];
        }
        #pragma unroll
        for (int s = 0; s < 3; ++s)
            cuv[s] = QS * (ca_qkv_w[l * 27 + 0 + s] * ck[0] +
                           ca_qkv_w[l * 27 + 3 + s] * ck[1] +
                           ca_qkv_w[l * 27 + 6 + s] * ck[2]);
        float cbv = QS * (ca_qkv_b[l * 9 + 0] * ck[0] +
                          ca_qkv_b[l * 9 + 1] * ck[1] +
                          ca_qkv_b[l * 9 + 2] * ck[2]);
        #pragma unroll
        for (int r = 0; r < 3; ++r)
            cvp[l][r] = ca_out_w[l * 9 + r * 3 + 0] * cv[0] +
                        ca_out_w[l * 9 + r * 3 + 1] * cv[1] +
                        ca_out_w[l * 9 + r * 3 + 2] * cv[2];
        // cbb uses TRUE gln1_b (score path), not the N1bF fold
        #pragma unroll
        for (int r = 0; r < 3; ++r) wcu[l][r] = cuv[r] * N1w[l][r];
        swcu[l] = wcu[l][0] + wcu[l][1] + wcu[l][2];
        cbb[l]  = cbv + cuv[0] * gln1_b[l * 3 + 0] + cuv[1] * gln1_b[l * 3 + 1]
                      + cuv[2] * gln1_b[l * 3 + 2];
    }

    // ---- pin the chain-critical persistent set (all scalar floats)
    #pragma unroll
    for (int l = 0; l < NL_; ++l) {
        #pragma unroll
        for (int r = 0; r < 6; ++r) {
            PIN(Bsq[l][r]);
            #pragma unroll
            for (int c = 0; c < 3; ++c) PIN(Wsq[l][r][c]);
        }
        PIN(swcu[l]); PIN(cbb[l]);
        #pragma unroll
        for (int r = 0; r < 3; ++r) {
            PIN(Bvp[l][r]); PIN(Bso[l][r]);
            PIN(N1w[l][r]); PIN(N1bF[l][r]); PIN(N2w[l][r]); PIN(N2bF[l][r]);
            PIN(wcu[l][r]); PIN(cvp[l][r]);
            #pragma unroll
            for (int c = 0; c < 3; ++c) PIN(Wvp[l][r][c]);
        }
    }

    // self-attn KV cache: lane j owns position j (sv holds Wso-transformed v')
    float sk[NL_][3] = {{0.f}}, sv[NL_][3] = {{0.f}};

    if (lane < 3) out[(b * S_ + 0) * 5 + lane] = 0.f;

    float y0 = 0.f, y1 = 0.f, y2 = 0.f;

    auto run_range = [&](int ibeg, int iend, auto nstc) {
        constexpr int NST = decltype(nstc)::value;
        constexpr int RL = (NST == 4) ? 15 : (NST == 5) ? 31 : 63;
        for (int i = ibeg; i < iend; ++i) {
            float msa = (lane <= i) ? 0.f : -1.0e30f;
            bool isme = (lane == i);
            #pragma unroll
            for (int l = 0; l < NL_; ++l) {
                // ---- FF-tail weights: ds_reads issued at layer top, PINned late
                float wv[40];
                {
                    const float4* fp = (const float4*)fst[l];
                    #pragma unroll
                    for (int k = 0; k < 10; ++k) {
                        float4 t4 = fp[k];
                        wv[4 * k + 0] = t4.x; wv[4 * k + 1] = t4.y;
                        wv[4 * k + 2] = t4.z; wv[4 * k + 3] = t4.w;
                    }
                }

                // ---- causal self-attention (q pre-scaled by QS; vp via Wvp fold)
                float q[3], kn[3], vp[3];
                #pragma unroll
                for (int r = 0; r < 3; ++r) {
                    kn[r] = fmaf(Wsq[l][3 + r][0], y0, fmaf(Wsq[l][3 + r][1], y1, fmaf(Wsq[l][3 + r][2], y2, Bsq[l][3 + r])));
                    q[r]  = fmaf(Wsq[l][r][0], y0, fmaf(Wsq[l][r][1], y1, fmaf(Wsq[l][r][2], y2, Bsq[l][r])));
                    vp[r] = fmaf(Wvp[l][r][0], y0, fmaf(Wvp[l][r][1], y1, fmaf(Wvp[l][r][2], y2, Bvp[l][r])));
                }
                if (isme) {
                    #pragma unroll
                    for (int r = 0; r < 3; ++r) { sk[l][r] = kn[r]; sv[l][r] = vp[r]; }
                }
                float sc = fmaf(q[0], sk[l][0], fmaf(q[1], sk[l][1], fmaf(q[2], sk[l][2], msa)));
                float e = __builtin_amdgcn_exp2f(sc);
                float se = e;
                float sa0 = e * sv[l][0];
                float sa1 = e * sv[l][1];
                float sa2 = e * sv[l][2];
                red16_4(se, sa0, sa1, sa2);
                if constexpr (NST >= 5) dpp4<0x142>(se, sa0, sa1, sa2);
                if constexpr (NST >= 6) dpp4<0x143>(se, sa0, sa1, sa2);
                float es = rlane<RL>(se);
                float S0 = rlane<RL>(sa0), S1 = rlane<RL>(sa1), S2 = rlane<RL>(sa2);
                // scale-invariant LN input: z = yb*es + S (no rcp on chain)
                float yb0 = y0 + Bso[l][0], yb1 = y1 + Bso[l][1], yb2 = y2 + Bso[l][2];
                float z0 = fmaf(yb0, es, S0), z1 = fmaf(yb1, es, S1), z2v = fmaf(yb2, es, S2);
                float ee = es * es;

                // ---- LN1 + folded CA score (rstd on chain; yc off-chain)
                float s1m = (z0 + z1) + z2v;
                float mu = s1m * (1.0f / 3.0f);
                float zw = fmaf(z0, wcu[l][0], fmaf(z1, wcu[l][1], z2v * wcu[l][2]));
                float inner = fmaf(-mu, swcu[l], zw);
                float s2m = fmaf(z0, z0, fmaf(z1, z1, z2v * z2v));
                float vpe = fmaf(s2m, (1.0f / 3.0f), fmaf(-mu, mu, 1e-5f * ee));
                float rstd1 = __builtin_amdgcn_rsqf(vpe);
                float sc2 = fmaf(rstd1, inner, cbb[l]);
                float e2 = __builtin_amdgcn_exp2f(sc2);
                float ce = e2;
                float ca0 = e2 * cvp[l][0];
                float ca1 = e2 * cvp[l][1];
                float ca2 = e2 * cvp[l][2];
                red16_4(ce, ca0, ca1, ca2);
                dpp4<0x142>(ce, ca0, ca1, ca2);
                dpp4<0x143>(ce, ca0, ca1, ca2);
                // yc = LN1-out + Bco directly via N1bF fold (off CA-reduce path)
                float yc0 = fmaf(z0 - mu, rstd1 * N1w[l][0], N1bF[l][0]);
                float yc1 = fmaf(z1 - mu, rstd1 * N1w[l][1], N1bF[l][1]);
                float yc2 = fmaf(z2v - mu, rstd1 * N1w[l][2], N1bF[l][2]);
                float cs = rlane<63>(ce);
                float C0 = rlane<63>(ca0), C1 = rlane<63>(ca1), C2 = rlane<63>(ca2);
                // scale-invariant again: g = yc*ce + C
                float g0 = fmaf(yc0, cs, C0), g1 = fmaf(yc1, cs, C1), g2 = fmaf(yc2, cs, C2);
                float cee = cs * cs;

                // ---- LN2 + folded FF1 (rstd2 on chain; yf off-chain)
                float t1m = (g0 + g1) + g2;
                float mu2 = t1m * (1.0f / 3.0f);
                float c20 = g0 - mu2, c21 = g1 - mu2, c22 = g2 - mu2;
                float t2m = fmaf(g0, g0, fmaf(g1, g1, g2 * g2));
                float vpe2 = fmaf(t2m, (1.0f / 3.0f), fmaf(-mu2, mu2, 1e-5f * cee));
                float rstd2 = __builtin_amdgcn_rsqf(vpe2);
                #pragma unroll
                for (int k = 0; k < 37; ++k) PIN(wv[k]);
                float d0 = fmaf(wv[0], c20, fmaf(wv[1],  c21, wv[2]  * c22));
                float d1 = fmaf(wv[3], c20, fmaf(wv[4],  c21, wv[5]  * c22));
                float d2 = fmaf(wv[6], c20, fmaf(wv[7],  c21, wv[8]  * c22));
                float d3 = fmaf(wv[9], c20, fmaf(wv[10], c21, wv[11] * c22));
                float h0 = fmaxf(fmaf(rstd2, d0, wv[12]), 0.f);
                float h1 = fmaxf(fmaf(rstd2, d1, wv[13]), 0.f);
                float h2 = fmaxf(fmaf(rstd2, d2, wv[14]), 0.f);
                float h3 = fmaxf(fmaf(rstd2, d3, wv[15]), 0.f);
                // yf = LN2-out + l2_b directly via N2bF fold
                float yf0 = fmaf(c20, rstd2 * N2w[l][0], N2bF[l][0]);
                float yf1 = fmaf(c21, rstd2 * N2w[l][1], N2bF[l][1]);
                float yf2 = fmaf(c22, rstd2 * N2w[l][2], N2bF[l][2]);
                float f0 = fmaf(wv[16], h0, fmaf(wv[17], h1, fmaf(wv[18], h2, fmaf(wv[19], h3, yf0))));
                float f1 = fmaf(wv[20], h0, fmaf(wv[21], h1, fmaf(wv[22], h2, fmaf(wv[23], h3, yf1))));
                float f2 = fmaf(wv[24], h0, fmaf(wv[25], h1, fmaf(wv[26], h2, fmaf(wv[27], h3, yf2))));
                ln3e(f0, f1, f2,
                     wv[31], wv[32], wv[33], wv[34], wv[35], wv[36],
                     y0, y1, y2);
            }
            if (lane == 0) {
                out[(b * S_ + i + 1) * 5 + 0] = y0;
                out[(b * S_ + i + 1) * 5 + 1] = y1;
                out[(b * S_ + i + 1) * 5 + 2] = y2;
            }
        }
    };

    run_range(0, 15, IC<4>{});
    run_range(15, 31, IC<5>{});
    run_range(31, S_ - 1, IC<6>{});
}

// ---------------------------------------------------------------------------
extern "C" void kernel_launch(void* const* d_in, const int* in_sizes, int n_in,
                              void* d_out, int out_size, void* d_ws, size_t ws_size,
                              hipStream_t stream) {
    const float* src  = (const float*)d_in[0];
    const float* wemb = (const float*)d_in[1];
    const float* semb = (const float*)d_in[2];

    float* mem = (float*)d_ws;           // [B,S,3] scratch
    float* out = (float*)d_out;          // [B,S,5]

    enc_kernel<<<B_, 512, 0, stream>>>(
        src, wemb, semb,
        (const float*)d_in[3],  (const float*)d_in[4],
        (const float*)d_in[5],  (const float*)d_in[6],
        (const float*)d_in[7],  (const float*)d_in[8],
        (const float*)d_in[9],  (const float*)d_in[10],
        (const float*)d_in[11], (const float*)d_in[12],
        (const float*)d_in[13], (const float*)d_in[14],
        (const float*)d_in[15], (const float*)d_in[16],
        (const float*)d_in[17], (const float*)d_in[18],
        mem, out);

    dec_kernel<<<B_, 64, 0, stream>>>(
        mem,
        (const float*)d_in[19], (const float*)d_in[20],
        (const float*)d_in[21], (const float*)d_in[22],
        (const float*)d_in[23], (const float*)d_in[24],
        (const float*)d_in[25], (const float*)d_in[26],
        (const float*)d_in[27], (const float*)d_in[28],
        (const float*)d_in[29], (const float*)d_in[30],
        (const float*)d_in[31], (const float*)d_in[32],
        (const float*)d_in[33], (const float*)d_in[34],
        (const float*)d_in[35], (const float*)d_in[36],
        out);
}